// Round 6
// baseline (789.465 us; speedup 1.0000x reference)
//
#include <hip/hip_runtime.h>

#define NG    32768
#define NN    128
#define NE    1024
#define NK    32
#define NB    (NG / 2)
#define RSTR  17                 // LDS table row stride in dwords (odd -> spread banks)
#define AWDW  (NN * RSTR)        // 2176 dwords per graph LDS table (8.5 KB)
#define PERS  2048               // persistent blocks (8/CU)
#define ITERS (NB / PERS)        // 8 pairs per block
#define GTDW  (NN * 16)          // global table dwords per graph (2048 = 8 KB)
#define GBDW  (2 * GTDW)         // per-block global region (4096 dw = 16 KB)

// R10: dual-pipe scatter. R6/R7/R8 establish dur ~= 220cyc x (LDS-atomic
// wave-instrs)/CU with ~zero intercept: the LDS atomic unit IS the kernel.
// Split each lane's 8 edges: 4 -> LDS ds_add_u32 (proven path), 4 ->
// global_atomic_add into an L2-resident per-block table in d_ws. The two
// atomic streams run on independent pipes; counts merge exactly as integers
// (numerics identical to R8). Persistent 2048 blocks x 8 pairs; 32MB ws.
__global__ __launch_bounds__(256, 8) void dcnn_split_kernel(
    const float* __restrict__ x,      // (G, N, 3)
    const int*   __restrict__ esrc,   // (G, E)
    const int*   __restrict__ edst,   // (G, E)
    const float* __restrict__ extx,   // (G, K, 3)
    const float* __restrict__ W, const float* __restrict__ M,
    const float* __restrict__ U, const float* __restrict__ V,
    const float* __restrict__ W1, const float* __restrict__ b1,
    const float* __restrict__ W2, const float* __restrict__ b2,
    unsigned* __restrict__ gws,       // workspace: PERS * GBDW dwords
    float* __restrict__ out)          // (B, 2)
{
    __shared__ unsigned A[2 * AWDW];  // 17.0 KB: one LDS table per graph slot
    __shared__ float pw[4][6];
    __shared__ float ge[2][3];

    const int t     = threadIdx.x;
    const int w     = t >> 6;
    const int lane  = t & 63;
    const int half  = w & 1;
    const int gslot = w >> 1;

    unsigned* __restrict__ greg = gws + (size_t)blockIdx.x * GBDW;

    for (int it = 0; it < ITERS; ++it) {
        const int pair = blockIdx.x + it * PERS;
        const int g    = gslot ? (pair + NB) : pair;

        const int gu = __builtin_amdgcn_readfirstlane(g);
        const float* __restrict__ xg = x + (size_t)gu * (NN * 3);

        // ---- edge lists: 8 edges/lane -------------------------------------
        const int4* sp = (const int4*)(esrc + (size_t)gu * NE);
        const int4* dp = (const int4*)(edst + (size_t)gu * NE);
        const int ebase = half * 128 + lane;
        const int4 s0 = sp[ebase], s1 = sp[ebase + 64];
        const int4 d0 = dp[ebase], d1 = dp[ebase + 64];

        float er0 = 0.f, er1 = 0.f, er2 = 0.f;
        if (half == 0 && lane < NK) {
            const float* ep = extx + (size_t)gu * (NK * 3) + lane * 3;
            er0 = ep[0]; er1 = ep[1]; er2 = ep[2];
        }

        // ---- zero LDS tables (4352 dw) + global region (4096 dw) ----------
        #pragma unroll
        for (int i = 0; i < 17; ++i) A[i * 256 + t] = 0u;
        {
            uint4* gz = (uint4*)(greg + t * 16);
            const uint4 z = make_uint4(0u, 0u, 0u, 0u);
            gz[0] = z; gz[1] = z; gz[2] = z; gz[3] = z;
        }
        __syncthreads();   // compiler drains vmcnt+lgkmcnt before s_barrier

        // ---- scatter: slots s0.* -> LDS pipe, slots s1.* -> L2 pipe -------
        unsigned* Aw = &A[gslot * AWDW];
        #define SCATL(SV, DV)                                                   \
            {                                                                   \
                const unsigned off = (unsigned)(size_t)&Aw[(DV) * RSTR + ((SV) >> 3)]; \
                const unsigned val = 1u << (4 * ((SV) & 7));                    \
                asm volatile("ds_add_u32 %0, %1" :: "v"(off), "v"(val) : "memory"); \
            }
        unsigned* gt = greg + gslot * GTDW;
        #define SCATG(SV, DV)                                                   \
            {                                                                   \
                const unsigned long long ad =                                   \
                    (unsigned long long)(size_t)(gt + (DV) * 16 + ((SV) >> 3)); \
                const unsigned val = 1u << (4 * ((SV) & 7));                    \
                asm volatile("global_atomic_add %0, %1, off" :: "v"(ad), "v"(val) : "memory"); \
            }
        SCATL(s0.x, d0.x) SCATG(s1.x, d1.x)
        SCATL(s0.y, d0.y) SCATG(s1.y, d1.y)
        SCATL(s0.z, d0.z) SCATG(s1.z, d1.z)
        SCATL(s0.w, d0.w) SCATG(s1.w, d1.w)
        #undef SCATL
        #undef SCATG

        asm volatile("s_waitcnt vmcnt(0) lgkmcnt(0)" ::: "memory");
        __syncthreads();

        // ---- readback global row (16 dw, sc0 = L1-bypass) -----------------
        const int row = half * 64 + lane;
        unsigned gq[16];
        {
            const unsigned long long ra =
                (unsigned long long)(size_t)(gt + row * 16);
            asm volatile(
                "global_load_dwordx4 %0, %4, off sc0\n\t"
                "global_load_dwordx4 %1, %4, off offset:16 sc0\n\t"
                "global_load_dwordx4 %2, %4, off offset:32 sc0\n\t"
                "global_load_dwordx4 %3, %4, off offset:48 sc0\n\t"
                "s_waitcnt vmcnt(0)"
                : "=v"(*(uint4*)&gq[0]), "=v"(*(uint4*)&gq[4]),
                  "=v"(*(uint4*)&gq[8]), "=v"(*(uint4*)&gq[12])
                : "v"(ra) : "memory");
        }
        __builtin_amdgcn_sched_barrier(0);

        // ---- agg = (A_lds + A_glb) @ x : dense unpack-MAC, s_load x -------
        const int r0 = row * RSTR;
        float ac0 = 0.f, ac1 = 0.f, ac2 = 0.f;
        #pragma unroll
        for (int j = 0; j < 16; ++j) {
            const unsigned d = Aw[r0 + j] + gq[j];   // exact integer merge
            float q[24];
            *(float4*)&q[0]  = *(const float4*)(xg + j * 24);
            *(float4*)&q[4]  = *(const float4*)(xg + j * 24 + 4);
            *(float4*)&q[8]  = *(const float4*)(xg + j * 24 + 8);
            *(float4*)&q[12] = *(const float4*)(xg + j * 24 + 12);
            *(float4*)&q[16] = *(const float4*)(xg + j * 24 + 16);
            *(float4*)&q[20] = *(const float4*)(xg + j * 24 + 20);
            #pragma unroll
            for (int o = 0; o < 8; ++o) {
                const float ca = (float)((d >> (4 * o)) & 15u);
                ac0 += ca * q[o * 3];
                ac1 += ca * q[o * 3 + 1];
                ac2 += ca * q[o * 3 + 2];
            }
        }

        // ---- h = relu(xW + aggM) for the owned node -----------------------
        float h0, h1, h2;
        {
            const float* xr = xg + row * 3;
            const float x0 = xr[0], x1 = xr[1], x2 = xr[2];
            h0 = fmaxf(x0 * W[0] + x1 * W[3] + x2 * W[6] +
                       ac0 * M[0] + ac1 * M[3] + ac2 * M[6], 0.f);
            h1 = fmaxf(x0 * W[1] + x1 * W[4] + x2 * W[7] +
                       ac0 * M[1] + ac1 * M[4] + ac2 * M[7], 0.f);
            h2 = fmaxf(x0 * W[2] + x1 * W[5] + x2 * W[8] +
                       ac0 * M[2] + ac1 * M[5] + ac2 * M[8], 0.f);
        }

        // ---- wave reduce (R8-proven shfl form) ----------------------------
        #pragma unroll
        for (int off = 16; off > 0; off >>= 1) {
            h0  += __shfl_xor(h0,  off);
            h1  += __shfl_xor(h1,  off);
            h2  += __shfl_xor(h2,  off);
            er0 += __shfl_xor(er0, off);
            er1 += __shfl_xor(er1, off);
            er2 += __shfl_xor(er2, off);
        }
        #define RL(v) (__uint_as_float(__builtin_amdgcn_readlane(__float_as_uint(v), 0)) + \
                       __uint_as_float(__builtin_amdgcn_readlane(__float_as_uint(v), 32)))
        if (lane == 0) {
            pw[w][0] = RL(h0);  pw[w][1] = RL(h1);  pw[w][2] = RL(h2);
            pw[w][3] = RL(er0); pw[w][4] = RL(er1); pw[w][5] = RL(er2);
        }
        #undef RL

        __syncthreads();

        // ---- per-graph tail ----------------------------------------------
        if (half == 0 && lane == 0) {
            const float H0 = pw[w][0] + pw[w + 1][0];
            const float H1 = pw[w][1] + pw[w + 1][1];
            const float H2 = pw[w][2] + pw[w + 1][2];
            const float E0 = pw[w][3] + pw[w + 1][3];
            const float E1 = pw[w][4] + pw[w + 1][4];
            const float E2 = pw[w][5] + pw[w + 1][5];

            const float mx = fmaxf(H0, fmaxf(H1, H2));
            const float e0 = __expf(H0 - mx), e1 = __expf(H1 - mx), e2 = __expf(H2 - mx);
            const float inv = 1.0f / (e0 + e1 + e2);
            const float emb0 = e0 * inv, emb1 = e1 * inv, emb2 = e2 * inv;

            float ext[3];
            #pragma unroll
            for (int e = 0; e < 3; ++e) {
                const float vv = emb0 * U[e] + emb1 * U[3 + e] + emb2 * U[6 + e]
                               + E0   * V[e] + E1   * V[3 + e] + E2   * V[6 + e];
                ext[e] = fmaxf(vv, 0.f);
            }
            const float mx2 = fmaxf(ext[0], fmaxf(ext[1], ext[2]));
            const float f0 = __expf(ext[0] - mx2), f1 = __expf(ext[1] - mx2), f2 = __expf(ext[2] - mx2);
            const float inv2 = 1.0f / (f0 + f1 + f2);
            ge[gslot][0] = f0 * inv2; ge[gslot][1] = f1 * inv2; ge[gslot][2] = f2 * inv2;
        }

        __syncthreads();

        // ---- pair combine on thread 0 ------------------------------------
        if (t == 0) {
            float tt[6];
            tt[0] = ge[0][0] * ge[1][0];
            tt[1] = ge[0][1] * ge[1][1];
            tt[2] = ge[0][2] * ge[1][2];
            tt[3] = ge[0][0] + ge[1][0];
            tt[4] = ge[0][1] + ge[1][1];
            tt[5] = ge[0][2] + ge[1][2];

            float hl[3];
            #pragma unroll
            for (int j = 0; j < 3; ++j) {
                float vv = b1[j];
                #pragma unroll
                for (int i = 0; i < 6; ++i) vv += tt[i] * W1[i * 3 + j];
                hl[j] = fmaxf(vv, 0.f);
            }

            const float l0 = b2[0] + hl[0] * W2[0] + hl[1] * W2[2] + hl[2] * W2[4];
            const float l1 = b2[1] + hl[0] * W2[1] + hl[1] * W2[3] + hl[2] * W2[5];
            const float mm = fmaxf(l0, l1);
            const float q0 = __expf(l0 - mm), q1 = __expf(l1 - mm);
            const float qi = 1.0f / (q0 + q1);
            out[(size_t)pair * 2    ] = q0 * qi;
            out[(size_t)pair * 2 + 1] = q1 * qi;
        }
        // next iteration's zero+__syncthreads orders table reuse
    }
}

// Fallback (= R8, best all-LDS version) if workspace is too small.
__global__ __launch_bounds__(256, 8) void dcnn_adj_kernel(
    const float* __restrict__ x, const int* __restrict__ esrc,
    const int* __restrict__ edst, const float* __restrict__ extx,
    const float* __restrict__ W, const float* __restrict__ M,
    const float* __restrict__ U, const float* __restrict__ V,
    const float* __restrict__ W1, const float* __restrict__ b1,
    const float* __restrict__ W2, const float* __restrict__ b2,
    float* __restrict__ out)
{
    __shared__ unsigned A[2 * AWDW];
    __shared__ float pw[4][6];
    __shared__ float ge[2][3];

    const int t     = threadIdx.x;
    const int w     = t >> 6;
    const int lane  = t & 63;
    const int half  = w & 1;
    const int gslot = w >> 1;
    const int pair  = blockIdx.x;
    const int g     = gslot ? (pair + NB) : pair;

    const int gu = __builtin_amdgcn_readfirstlane(g);
    const float* __restrict__ xg = x + (size_t)gu * (NN * 3);

    const int4* sp = (const int4*)(esrc + (size_t)gu * NE);
    const int4* dp = (const int4*)(edst + (size_t)gu * NE);
    const int ebase = half * 128 + lane;
    const int4 s0 = sp[ebase], s1 = sp[ebase + 64];
    const int4 d0 = dp[ebase], d1 = dp[ebase + 64];

    float er0 = 0.f, er1 = 0.f, er2 = 0.f;
    if (half == 0 && lane < NK) {
        const float* ep = extx + (size_t)gu * (NK * 3) + lane * 3;
        er0 = ep[0]; er1 = ep[1]; er2 = ep[2];
    }

    #pragma unroll
    for (int i = 0; i < 17; ++i) A[i * 256 + t] = 0u;
    __syncthreads();

    unsigned* Aw = &A[gslot * AWDW];
    #define SCAT(SV, DV)                                                    \
        {                                                                   \
            const unsigned off = (unsigned)(size_t)&Aw[(DV) * RSTR + ((SV) >> 3)]; \
            const unsigned val = 1u << (4 * ((SV) & 7));                    \
            asm volatile("ds_add_u32 %0, %1" :: "v"(off), "v"(val) : "memory"); \
        }
    SCAT(s0.x, d0.x) SCAT(s0.y, d0.y) SCAT(s0.z, d0.z) SCAT(s0.w, d0.w)
    SCAT(s1.x, d1.x) SCAT(s1.y, d1.y) SCAT(s1.z, d1.z) SCAT(s1.w, d1.w)
    #undef SCAT

    asm volatile("s_waitcnt lgkmcnt(0)" ::: "memory");
    __syncthreads();

    const int row = half * 64 + lane;
    const int r0  = row * RSTR;
    float ac0 = 0.f, ac1 = 0.f, ac2 = 0.f;

    #pragma unroll
    for (int j = 0; j < 16; ++j) {
        const unsigned d = Aw[r0 + j];
        float q[24];
        *(float4*)&q[0]  = *(const float4*)(xg + j * 24);
        *(float4*)&q[4]  = *(const float4*)(xg + j * 24 + 4);
        *(float4*)&q[8]  = *(const float4*)(xg + j * 24 + 8);
        *(float4*)&q[12] = *(const float4*)(xg + j * 24 + 12);
        *(float4*)&q[16] = *(const float4*)(xg + j * 24 + 16);
        *(float4*)&q[20] = *(const float4*)(xg + j * 24 + 20);
        #pragma unroll
        for (int o = 0; o < 8; ++o) {
            const float ca = (float)((d >> (4 * o)) & 15u);
            ac0 += ca * q[o * 3];
            ac1 += ca * q[o * 3 + 1];
            ac2 += ca * q[o * 3 + 2];
        }
    }

    float h0, h1, h2;
    {
        const float* xr = xg + row * 3;
        const float x0 = xr[0], x1 = xr[1], x2 = xr[2];
        h0 = fmaxf(x0 * W[0] + x1 * W[3] + x2 * W[6] +
                   ac0 * M[0] + ac1 * M[3] + ac2 * M[6], 0.f);
        h1 = fmaxf(x0 * W[1] + x1 * W[4] + x2 * W[7] +
                   ac0 * M[1] + ac1 * M[4] + ac2 * M[7], 0.f);
        h2 = fmaxf(x0 * W[2] + x1 * W[5] + x2 * W[8] +
                   ac0 * M[2] + ac1 * M[5] + ac2 * M[8], 0.f);
    }

    #pragma unroll
    for (int off = 16; off > 0; off >>= 1) {
        h0  += __shfl_xor(h0,  off);
        h1  += __shfl_xor(h1,  off);
        h2  += __shfl_xor(h2,  off);
        er0 += __shfl_xor(er0, off);
        er1 += __shfl_xor(er1, off);
        er2 += __shfl_xor(er2, off);
    }
    #define RL(v) (__uint_as_float(__builtin_amdgcn_readlane(__float_as_uint(v), 0)) + \
                   __uint_as_float(__builtin_amdgcn_readlane(__float_as_uint(v), 32)))
    if (lane == 0) {
        pw[w][0] = RL(h0);  pw[w][1] = RL(h1);  pw[w][2] = RL(h2);
        pw[w][3] = RL(er0); pw[w][4] = RL(er1); pw[w][5] = RL(er2);
    }
    #undef RL

    __syncthreads();

    if (half == 0 && lane == 0) {
        const float H0 = pw[w][0] + pw[w + 1][0];
        const float H1 = pw[w][1] + pw[w + 1][1];
        const float H2 = pw[w][2] + pw[w + 1][2];
        const float E0 = pw[w][3] + pw[w + 1][3];
        const float E1 = pw[w][4] + pw[w + 1][4];
        const float E2 = pw[w][5] + pw[w + 1][5];

        const float mx = fmaxf(H0, fmaxf(H1, H2));
        const float e0 = __expf(H0 - mx), e1 = __expf(H1 - mx), e2 = __expf(H2 - mx);
        const float inv = 1.0f / (e0 + e1 + e2);
        const float emb0 = e0 * inv, emb1 = e1 * inv, emb2 = e2 * inv;

        float ext[3];
        #pragma unroll
        for (int e = 0; e < 3; ++e) {
            const float vv = emb0 * U[e] + emb1 * U[3 + e] + emb2 * U[6 + e]
                           + E0   * V[e] + E1   * V[3 + e] + E2   * V[6 + e];
            ext[e] = fmaxf(vv, 0.f);
        }
        const float mx2 = fmaxf(ext[0], fmaxf(ext[1], ext[2]));
        const float f0 = __expf(ext[0] - mx2), f1 = __expf(ext[1] - mx2), f2 = __expf(ext[2] - mx2);
        const float inv2 = 1.0f / (f0 + f1 + f2);
        ge[gslot][0] = f0 * inv2; ge[gslot][1] = f1 * inv2; ge[gslot][2] = f2 * inv2;
    }

    __syncthreads();

    if (t == 0) {
        float tt[6];
        tt[0] = ge[0][0] * ge[1][0];
        tt[1] = ge[0][1] * ge[1][1];
        tt[2] = ge[0][2] * ge[1][2];
        tt[3] = ge[0][0] + ge[1][0];
        tt[4] = ge[0][1] + ge[1][1];
        tt[5] = ge[0][2] + ge[1][2];

        float hl[3];
        #pragma unroll
        for (int j = 0; j < 3; ++j) {
            float vv = b1[j];
            #pragma unroll
            for (int i = 0; i < 6; ++i) vv += tt[i] * W1[i * 3 + j];
            hl[j] = fmaxf(vv, 0.f);
        }

        const float l0 = b2[0] + hl[0] * W2[0] + hl[1] * W2[2] + hl[2] * W2[4];
        const float l1 = b2[1] + hl[0] * W2[1] + hl[1] * W2[3] + hl[2] * W2[5];
        const float mm = fmaxf(l0, l1);
        const float q0 = __expf(l0 - mm), q1 = __expf(l1 - mm);
        const float qi = 1.0f / (q0 + q1);
        out[(size_t)pair * 2    ] = q0 * qi;
        out[(size_t)pair * 2 + 1] = q1 * qi;
    }
}

extern "C" void kernel_launch(void* const* d_in, const int* in_sizes, int n_in,
                              void* d_out, int out_size, void* d_ws, size_t ws_size,
                              hipStream_t stream) {
    const float* x    = (const float*)d_in[0];
    const int*   esrc = (const int*)  d_in[1];
    const int*   edst = (const int*)  d_in[2];
    const float* extx = (const float*)d_in[3];
    const float* W    = (const float*)d_in[4];
    const float* M    = (const float*)d_in[5];
    const float* U    = (const float*)d_in[6];
    const float* V    = (const float*)d_in[7];
    const float* W1   = (const float*)d_in[8];
    const float* b1   = (const float*)d_in[9];
    const float* W2   = (const float*)d_in[10];
    const float* b2   = (const float*)d_in[11];
    float* out = (float*)d_out;

    const size_t need = (size_t)PERS * GBDW * sizeof(unsigned);   // 32 MiB
    if (d_ws != nullptr && ws_size >= need) {
        dcnn_split_kernel<<<PERS, 256, 0, stream>>>(
            x, esrc, edst, extx, W, M, U, V, W1, b1, W2, b2,
            (unsigned*)d_ws, out);
    } else {
        dcnn_adj_kernel<<<NB, 256, 0, stream>>>(
            x, esrc, edst, extx, W, M, U, V, W1, b1, W2, b2, out);
    }
}

// Round 8
// 376.374 us; speedup vs baseline: 2.0976x; 2.0976x over previous
//
#include <hip/hip_runtime.h>

#define NG    32768
#define NN    128
#define NE    1024
#define NK    32
#define NB    (NG / 2)
#define RSTR  17                 // A row stride in dwords (odd -> conflict-free)
#define AWDW  (NN * RSTR)        // 2176 dwords per wave (8.5 KB)

// R11b = R7 resubmitted verbatim (two infra failures; kernel never ran.
// R7 itself measured 163us dispatch / 378.6us bench, absmax 0.0).
// Model (R6-R10 fit): dispatch time == LDS-atomic lane-ops x ~3cyc, serialized
// per CU. G*E/256CU*3cyc/2.4GHz = 164us = measured. Occupancy (R8), bank
// spread (R6), non-atomic DS traffic (R9), and global-atomic offload (R10)
// are all measured non-levers. This kernel sits on that floor; everything
// else (VALU MAC, s_load x reads, reductions) hides under the atomic phase.
__global__ __launch_bounds__(256) void dcnn_adj_kernel(
    const float* __restrict__ x,      // (G, N, 3)
    const int*   __restrict__ esrc,   // (G, E)
    const int*   __restrict__ edst,   // (G, E)
    const float* __restrict__ extx,   // (G, K, 3)
    const float* __restrict__ W,      // (3,3)
    const float* __restrict__ M,      // (3,3)
    const float* __restrict__ U,      // (3,3)
    const float* __restrict__ V,      // (3,3)
    const float* __restrict__ W1,     // (6,3)
    const float* __restrict__ b1,     // (3,)
    const float* __restrict__ W2,     // (3,2)
    const float* __restrict__ b2,     // (2,)
    float* __restrict__ out)          // (B, 2)
{
    __shared__ unsigned A[4 * AWDW];  // 34.8 KB
    __shared__ float ge[4][3];

    const int t    = threadIdx.x;
    const int w    = t >> 6;
    const int lane = t & 63;
    const int pair = blockIdx.x * 2 + (w >> 1);
    const int g    = (w & 1) ? (pair + NB) : pair;

    // wave-uniform graph id as an SGPR: makes xg provably uniform so the
    // dense-loop x reads compile to s_load (scalar cache), not vector loads.
    const int gu = __builtin_amdgcn_readfirstlane(g);

    const float* __restrict__ xg = x + (size_t)gu * (NN * 3);

    // ---- edge lists -> registers (coalesced int4) -------------------------
    const int4* sp = (const int4*)(esrc + (size_t)gu * NE);
    const int4* dp = (const int4*)(edst + (size_t)gu * NE);
    const int4 s0 = sp[lane], s1 = sp[lane + 64], s2 = sp[lane + 128], s3 = sp[lane + 192];
    const int4 d0 = dp[lane], d1 = dp[lane + 64], d2 = dp[lane + 128], d3 = dp[lane + 192];

    // ext row (lanes 0..31)
    float er0 = 0.f, er1 = 0.f, er2 = 0.f;
    if (lane < NK) {
        const float* ep = extx + (size_t)gu * (NK * 3) + lane * 3;
        er0 = ep[0]; er1 = ep[1]; er2 = ep[2];
    }

    // ---- zero A (2176 dwords/wave, conflict-free) -------------------------
    unsigned* Aw = &A[w * AWDW];
    #pragma unroll
    for (int i = 0; i < 34; ++i) {
        const int idx = i * 64 + lane;
        if (idx < AWDW) Aw[idx] = 0u;
    }

    __builtin_amdgcn_wave_barrier();   // DS ops in-order per wave

    // ---- build adjacency counts: ONE no-return ds_add_u32 per edge --------
    #define SCAT(SV, DV)                                                    \
        {                                                                   \
            const unsigned off = (unsigned)(size_t)&Aw[(DV) * RSTR + ((SV) >> 3)]; \
            const unsigned val = 1u << (4 * ((SV) & 7));                    \
            asm volatile("ds_add_u32 %0, %1" :: "v"(off), "v"(val) : "memory"); \
        }
    SCAT(s0.x, d0.x) SCAT(s0.y, d0.y) SCAT(s0.z, d0.z) SCAT(s0.w, d0.w)
    SCAT(s1.x, d1.x) SCAT(s1.y, d1.y) SCAT(s1.z, d1.z) SCAT(s1.w, d1.w)
    SCAT(s2.x, d2.x) SCAT(s2.y, d2.y) SCAT(s2.z, d2.z) SCAT(s2.w, d2.w)
    SCAT(s3.x, d3.x) SCAT(s3.y, d3.y) SCAT(s3.z, d3.z) SCAT(s3.w, d3.w)
    #undef SCAT

    // drain the scatter before reading A (asm hid the dependency)
    asm volatile("s_waitcnt lgkmcnt(0)" ::: "memory");
    __builtin_amdgcn_wave_barrier();

    // ---- agg = A @ x : lane owns dst rows {lane, lane+64}, agg in regs ----
    float ac0 = 0.f, ac1 = 0.f, ac2 = 0.f;   // node lane
    float ac3 = 0.f, ac4 = 0.f, ac5 = 0.f;   // node lane+64
    const int r0 = lane * RSTR;
    const int r1 = (lane + 64) * RSTR;

    #pragma unroll
    for (int j = 0; j < 16; ++j) {
        const unsigned da = Aw[r0 + j];
        const unsigned db = Aw[r1 + j];
        // x for srcs j*8 .. j*8+7 : 24 floats, wave-uniform address -> s_load
        float q[24];
        *(float4*)&q[0]  = *(const float4*)(xg + j * 24);
        *(float4*)&q[4]  = *(const float4*)(xg + j * 24 + 4);
        *(float4*)&q[8]  = *(const float4*)(xg + j * 24 + 8);
        *(float4*)&q[12] = *(const float4*)(xg + j * 24 + 12);
        *(float4*)&q[16] = *(const float4*)(xg + j * 24 + 16);
        *(float4*)&q[20] = *(const float4*)(xg + j * 24 + 20);
        #pragma unroll
        for (int o = 0; o < 8; ++o) {
            const float ca = (float)((da >> (4 * o)) & 15u);
            const float cb = (float)((db >> (4 * o)) & 15u);
            const float xs0 = q[o * 3], xs1 = q[o * 3 + 1], xs2 = q[o * 3 + 2];
            ac0 += ca * xs0; ac1 += ca * xs1; ac2 += ca * xs2;
            ac3 += cb * xs0; ac4 += cb * xs1; ac5 += cb * xs2;
        }
    }

    // ---- per-node h = relu(xW + aggM) for the 2 owned nodes ---------------
    float h0, h1, h2;
    {
        const float* xr = xg + lane * 3;
        const float x0 = xr[0], x1 = xr[1], x2 = xr[2];
        h0 = fmaxf(x0 * W[0] + x1 * W[3] + x2 * W[6] +
                   ac0 * M[0] + ac1 * M[3] + ac2 * M[6], 0.f);
        h1 = fmaxf(x0 * W[1] + x1 * W[4] + x2 * W[7] +
                   ac0 * M[1] + ac1 * M[4] + ac2 * M[7], 0.f);
        h2 = fmaxf(x0 * W[2] + x1 * W[5] + x2 * W[8] +
                   ac0 * M[2] + ac1 * M[5] + ac2 * M[8], 0.f);
    }
    {
        const float* xr = xg + (lane + 64) * 3;
        const float x0 = xr[0], x1 = xr[1], x2 = xr[2];
        h0 += fmaxf(x0 * W[0] + x1 * W[3] + x2 * W[6] +
                    ac3 * M[0] + ac4 * M[3] + ac5 * M[6], 0.f);
        h1 += fmaxf(x0 * W[1] + x1 * W[4] + x2 * W[7] +
                    ac3 * M[1] + ac4 * M[4] + ac5 * M[7], 0.f);
        h2 += fmaxf(x0 * W[2] + x1 * W[5] + x2 * W[8] +
                    ac3 * M[2] + ac4 * M[5] + ac5 * M[8], 0.f);
    }

    // ---- reduce within 32-lane halves, combine halves via readlane --------
    #pragma unroll
    for (int off = 16; off > 0; off >>= 1) {
        h0  += __shfl_xor(h0,  off);
        h1  += __shfl_xor(h1,  off);
        h2  += __shfl_xor(h2,  off);
        er0 += __shfl_xor(er0, off);
        er1 += __shfl_xor(er1, off);
        er2 += __shfl_xor(er2, off);
    }
    #define RL(v) (__uint_as_float(__builtin_amdgcn_readlane(__float_as_uint(v), 0)) + \
                   __uint_as_float(__builtin_amdgcn_readlane(__float_as_uint(v), 32)))
    const float H0 = RL(h0), H1 = RL(h1), H2 = RL(h2);
    const float E0 = RL(er0), E1 = RL(er1), E2 = RL(er2);
    #undef RL

    // ---- per-wave tail: emb softmax -> ext MLP -> g_emb -------------------
    if (lane == 0) {
        const float mx = fmaxf(H0, fmaxf(H1, H2));
        const float e0 = __expf(H0 - mx), e1 = __expf(H1 - mx), e2 = __expf(H2 - mx);
        const float inv = 1.0f / (e0 + e1 + e2);
        const float emb0 = e0 * inv, emb1 = e1 * inv, emb2 = e2 * inv;

        float ext[3];
        #pragma unroll
        for (int e = 0; e < 3; ++e) {
            const float vv = emb0 * U[e] + emb1 * U[3 + e] + emb2 * U[6 + e]
                           + E0   * V[e] + E1   * V[3 + e] + E2   * V[6 + e];
            ext[e] = fmaxf(vv, 0.f);
        }
        const float mx2 = fmaxf(ext[0], fmaxf(ext[1], ext[2]));
        const float f0 = __expf(ext[0] - mx2), f1 = __expf(ext[1] - mx2), f2 = __expf(ext[2] - mx2);
        const float inv2 = 1.0f / (f0 + f1 + f2);
        ge[w][0] = f0 * inv2; ge[w][1] = f1 * inv2; ge[w][2] = f2 * inv2;
    }

    __syncthreads();

    // ---- pair combine on lane 0 of waves 0 and 2 --------------------------
    if ((w & 1) == 0 && lane == 0) {
        float tt[6];
        tt[0] = ge[w][0] * ge[w + 1][0];
        tt[1] = ge[w][1] * ge[w + 1][1];
        tt[2] = ge[w][2] * ge[w + 1][2];
        tt[3] = ge[w][0] + ge[w + 1][0];
        tt[4] = ge[w][1] + ge[w + 1][1];
        tt[5] = ge[w][2] + ge[w + 1][2];

        float hl[3];
        #pragma unroll
        for (int j = 0; j < 3; ++j) {
            float vv = b1[j];
            #pragma unroll
            for (int i = 0; i < 6; ++i) vv += tt[i] * W1[i * 3 + j];
            hl[j] = fmaxf(vv, 0.f);
        }

        const float l0 = b2[0] + hl[0] * W2[0] + hl[1] * W2[2] + hl[2] * W2[4];
        const float l1 = b2[1] + hl[0] * W2[1] + hl[1] * W2[3] + hl[2] * W2[5];
        const float mm = fmaxf(l0, l1);
        const float q0 = __expf(l0 - mm), q1 = __expf(l1 - mm);
        const float qi = 1.0f / (q0 + q1);
        out[(size_t)pair * 2    ] = q0 * qi;
        out[(size_t)pair * 2 + 1] = q1 * qi;
    }
}

extern "C" void kernel_launch(void* const* d_in, const int* in_sizes, int n_in,
                              void* d_out, int out_size, void* d_ws, size_t ws_size,
                              hipStream_t stream) {
    const float* x    = (const float*)d_in[0];
    const int*   esrc = (const int*)  d_in[1];
    const int*   edst = (const int*)  d_in[2];
    const float* extx = (const float*)d_in[3];
    const float* W    = (const float*)d_in[4];
    const float* M    = (const float*)d_in[5];
    const float* U    = (const float*)d_in[6];
    const float* V    = (const float*)d_in[7];
    const float* W1   = (const float*)d_in[8];
    const float* b1   = (const float*)d_in[9];
    const float* W2   = (const float*)d_in[10];
    const float* b2   = (const float*)d_in[11];
    float* out = (float*)d_out;

    dcnn_adj_kernel<<<NB / 2, 256, 0, stream>>>(
        x, esrc, edst, extx, W, M, U, V, W1, b1, W2, b2, out);
}